// Round 1
// baseline (435.653 us; speedup 1.0000x reference)
//
#include <hip/hip_runtime.h>

// B=8, C=256, K=64, H=W=64, HW=4096
using bf16x8 = __attribute__((ext_vector_type(8))) short;
using f32x4  = __attribute__((ext_vector_type(4))) float;

#define DEVI static __device__ __forceinline__

DEVI unsigned short f2bf(float f){
  unsigned u = __builtin_bit_cast(unsigned, f);
  u += 0x7fffu + ((u >> 16) & 1u);
  return (unsigned short)(u >> 16);
}
DEVI float bf2f(unsigned short h){
  unsigned u = ((unsigned)h) << 16;
  return __builtin_bit_cast(float, u);
}
DEVI f32x4 zf4(){ f32x4 z; z[0]=0.f; z[1]=0.f; z[2]=0.f; z[3]=0.f; return z; }

// ---------------------------------------------------------------------------
// k_prep: transpose 1x1 weights to [c][k]; pack 3x3 weights to [tau][o][c] bf16
// ---------------------------------------------------------------------------
__global__ __launch_bounds__(256) void k_prep(
    const float* __restrict__ top_w, const float* __restrict__ cen_w,
    const float* __restrict__ bot_w, const float* __restrict__ out_w,
    float* __restrict__ wTt, float* __restrict__ wTc,
    unsigned short* __restrict__ apb, unsigned short* __restrict__ apo){
  int i = blockIdx.x * 256 + threadIdx.x;
  if (i < 64 * 256){
    int c = i >> 6, k = i & 63;
    wTt[i] = top_w[k * 256 + c];
    wTc[i] = cen_w[k * 256 + c];
  }
  if (i < 9 * 256 * 256){
    int tau = i >> 16, oc = i & 65535;   // oc = o*256+c
    apb[i] = f2bf(bot_w[oc * 9 + tau]);
    apo[i] = f2bf(out_w[oc * 9 + tau]);
  }
}

// ---------------------------------------------------------------------------
// k_topcenter: top/center = W[64,256] @ x[256,4096] per batch, fp32 VALU,
// stored transposed [n][k] as hi/lo bf16 split.
// grid (16 ntiles, 2 z, 8 b), 256 thr. Thread t owns column n = nt*256+t.
// ---------------------------------------------------------------------------
__global__ __launch_bounds__(256) void k_topcenter(
    const float* __restrict__ x,
    const float* __restrict__ wTt, const float* __restrict__ wTc,
    const float* __restrict__ top_b, const float* __restrict__ cen_b,
    unsigned short* __restrict__ tTh, unsigned short* __restrict__ tTl,
    unsigned short* __restrict__ cTh, unsigned short* __restrict__ cTl){
  __shared__ float xs[16][256];
  int b = blockIdx.z, z = blockIdx.y, nt = blockIdx.x;
  int t = threadIdx.x;
  int n = nt * 256 + t;
  const float* wT   = z ? wTc : wTt;
  const float* bias = z ? cen_b : top_b;
  unsigned short* oh = z ? cTh : tTh;
  unsigned short* ol = z ? cTl : tTl;
  const float* xb = x + ((size_t)b << 20);

  float acc[64];
  #pragma unroll
  for (int k = 0; k < 64; k++) acc[k] = 0.f;

  for (int cc = 0; cc < 256; cc += 16){
    __syncthreads();
    #pragma unroll
    for (int r = 0; r < 16; r++)
      xs[r][t] = xb[((size_t)(cc + r) << 12) + nt * 256 + t];
    __syncthreads();
    #pragma unroll
    for (int r = 0; r < 16; r++){
      float xv = xs[r][t];
      const float* wr = wT + (cc + r) * 64;   // uniform -> scalar loads
      #pragma unroll
      for (int k = 0; k < 64; k++) acc[k] = fmaf(wr[k], xv, acc[k]);
    }
  }
  size_t base = (((size_t)b << 12) + n) * 64;
  #pragma unroll
  for (int k8 = 0; k8 < 64; k8 += 8){
    bf16x8 vh, vl;
    #pragma unroll
    for (int j = 0; j < 8; j++){
      float v = acc[k8 + j] + bias[k8 + j];
      unsigned short h = f2bf(v);
      vh[j] = (short)h;
      vl[j] = (short)f2bf(v - bf2f(h));
    }
    *(bf16x8*)(oh + base + k8) = vh;
    *(bf16x8*)(ol + base + k8) = vl;
  }
}

// ---------------------------------------------------------------------------
// k_trans: channels-first fp32 (+ optional U/Z residual) -> channels-last bf16
// out[b][p][c] = bf16( x[b][c][p] + (U ? U[b][c*4096+p]/Z[b] : 0) )
// grid (128 ptiles, 8 ctiles, 8 b), 256 thr (32x8 tile transpose)
// ---------------------------------------------------------------------------
__global__ __launch_bounds__(256) void k_trans(
    const float* __restrict__ x, const float* __restrict__ U,
    const float* __restrict__ Z, unsigned short* __restrict__ ocl){
  __shared__ float tile[32][33];
  int b = blockIdx.z, ct = blockIdx.y, pt = blockIdx.x;
  int tx = threadIdx.x & 31, ty = threadIdx.x >> 5;
  size_t bo = (size_t)b << 20;
  int c0 = ct * 32, p0 = pt * 32;
  float invZ = (U != nullptr) ? (1.0f / Z[b]) : 0.0f;
  #pragma unroll
  for (int q = 0; q < 4; q++){
    int c = c0 + ty + q * 8;
    size_t idx = bo + ((size_t)c << 12) + p0 + tx;
    float v = x[idx];
    if (U) v = fmaf(U[idx], invZ, v);
    tile[ty + q * 8][tx] = v;
  }
  __syncthreads();
  #pragma unroll
  for (int q = 0; q < 4; q++){
    int p = p0 + ty + q * 8;
    ocl[bo + ((size_t)p << 8) + c0 + tx] = f2bf(tile[tx][ty + q * 8]);
  }
}

// ---------------------------------------------------------------------------
// k_conv3: 3x3 SAME conv as 9-shift MFMA GEMM.
// in: channels-last bf16 [b][p][c]; weights apack [tau][o][c] bf16.
// OUTF32=0 -> bf16 out [b][o][p] (x_bottom); OUTF32=1 -> f32 out (final).
// grid 512 linear (b = bid&7 for XCD locality), 256 thr (4 waves).
// Block tile: [256 o][64 p]; wave w owns o in [w*64, w*64+64).
// ---------------------------------------------------------------------------
template<int OUTF32>
__global__ __launch_bounds__(256) void k_conv3(
    const unsigned short* __restrict__ incl,
    const unsigned short* __restrict__ ap,
    const float* __restrict__ bias, void* __restrict__ outp){
  __shared__ unsigned short Bt[64][40];   // [p][c-chunk 32], 80B rows
  int bid = blockIdx.x;
  int b = bid & 7, pt = bid >> 3;
  int t = threadIdx.x, wv = t >> 6, l = t & 63, lr = l & 15, g = l >> 4;
  int p0 = pt * 64;
  const unsigned short* inb = incl + ((size_t)b << 20);

  f32x4 acc[4][4];
  #pragma unroll
  for (int a = 0; a < 4; a++)
    #pragma unroll
    for (int c = 0; c < 4; c++) acc[a][c] = zf4();

  int sp = t >> 2, sco = (t & 3) * 8;
  int pg = p0 + sp, sh = pg >> 6, sw = pg & 63;

  for (int tau = 0; tau < 9; tau++){
    int dy = tau / 3 - 1, dx = tau % 3 - 1;
    int h2 = sh + dy, w2 = sw + dx;
    bool valid = ((unsigned)h2 < 64u) && ((unsigned)w2 < 64u);
    int q = valid ? (h2 * 64 + w2) : 0;
    const unsigned short* srow = inb + ((size_t)q << 8);
    for (int cc = 0; cc < 256; cc += 32){
      __syncthreads();
      bf16x8 v = {0,0,0,0,0,0,0,0};
      if (valid) v = *(const bf16x8*)(srow + cc + sco);
      *(bf16x8*)(&Bt[sp][sco]) = v;
      __syncthreads();
      bf16x8 af[4], bfv[4];
      #pragma unroll
      for (int of = 0; of < 4; of++){
        int o = wv * 64 + of * 16 + lr;
        af[of] = *(const bf16x8*)(ap + ((size_t)tau << 16) + (o << 8) + cc + 8 * g);
      }
      #pragma unroll
      for (int pf = 0; pf < 4; pf++)
        bfv[pf] = *(const bf16x8*)(&Bt[pf * 16 + lr][8 * g]);
      #pragma unroll
      for (int of = 0; of < 4; of++)
        #pragma unroll
        for (int pf = 0; pf < 4; pf++)
          acc[of][pf] = __builtin_amdgcn_mfma_f32_16x16x32_bf16(af[of], bfv[pf], acc[of][pf], 0, 0, 0);
    }
  }
  #pragma unroll
  for (int of = 0; of < 4; of++){
    int ob = wv * 64 + of * 16 + 4 * g;
    #pragma unroll
    for (int pf = 0; pf < 4; pf++){
      int p = p0 + pf * 16 + lr;
      #pragma unroll
      for (int i = 0; i < 4; i++){
        int o = ob + i;
        float v = acc[of][pf][i] + bias[o];
        size_t oi = ((size_t)b << 20) + ((size_t)o << 12) + p;
        if (OUTF32) ((float*)outp)[oi] = v;
        else        ((unsigned short*)outp)[oi] = f2bf(v);
      }
    }
  }
}

// ---------------------------------------------------------------------------
// k_pv: fused S^T = topT x cenT (split-bf16), exp, PV vs x_bot, row-sums.
// Block: batch b, n-tile of 64 rows; loop m in steps of 64.
// Wave w computes S^T rows m_local in [w*16,w*16+16) x all 64 n.
// PV: wave w owns c in [w*64, w*64+64), all 64 n.
// U[b][n*256+c] unnormalized fp32 (== channels-first scrambled layout).
// ---------------------------------------------------------------------------
__global__ __launch_bounds__(256) void k_pv(
    const unsigned short* __restrict__ tTh, const unsigned short* __restrict__ tTl,
    const unsigned short* __restrict__ cTh, const unsigned short* __restrict__ cTl,
    const unsigned short* __restrict__ xbot,
    float* __restrict__ U, float* __restrict__ rsum){
  __shared__ unsigned short Pl[64][72];    // [n][m] 144B rows
  __shared__ unsigned short Xl[256][72];   // [c][m] 144B rows
  __shared__ float rred[4][4][16];
  int bid = blockIdx.x;
  int b = bid & 7, nt = bid >> 3;
  int t = threadIdx.x, wv = t >> 6, l = t & 63, lr = l & 15, g = l >> 4;
  int n0 = nt * 64;
  const unsigned short* xbb = xbot + ((size_t)b << 20);

  // centerT fragments, loop-invariant, kept in registers
  bf16x8 ch[2][4], cl[2][4];
  #pragma unroll
  for (int kf = 0; kf < 2; kf++)
    #pragma unroll
    for (int nf = 0; nf < 4; nf++){
      size_t ci = (((size_t)b << 12) + n0 + nf * 16 + lr) * 64 + kf * 32 + 8 * g;
      ch[kf][nf] = *(const bf16x8*)(cTh + ci);
      cl[kf][nf] = *(const bf16x8*)(cTl + ci);
    }

  f32x4 accO[4][4];
  #pragma unroll
  for (int a = 0; a < 4; a++)
    #pragma unroll
    for (int c = 0; c < 4; c++) accO[a][c] = zf4();
  float racc[4] = {0.f, 0.f, 0.f, 0.f};

  int sc = t >> 3, smo = (t & 7) * 8;   // x_bot staging: 8 threads/row

  for (int ms = 0; ms < 64; ms++){
    int m0 = ms * 64;
    // prefetch x_bot tile to regs (written to LDS after the barrier)
    bf16x8 xst[8];
    #pragma unroll
    for (int u = 0; u < 8; u++)
      xst[u] = *(const bf16x8*)(xbb + ((size_t)(sc + u * 32) << 12) + m0 + smo);

    // S^T = topT(hi+lo) x cenT(hi+lo), dropping lo*lo
    f32x4 sa[4];
    #pragma unroll
    for (int nf = 0; nf < 4; nf++) sa[nf] = zf4();
    #pragma unroll
    for (int kf = 0; kf < 2; kf++){
      size_t ti = (((size_t)b << 12) + m0 + wv * 16 + lr) * 64 + kf * 32 + 8 * g;
      bf16x8 ah = *(const bf16x8*)(tTh + ti);
      bf16x8 al = *(const bf16x8*)(tTl + ti);
      #pragma unroll
      for (int nf = 0; nf < 4; nf++){
        sa[nf] = __builtin_amdgcn_mfma_f32_16x16x32_bf16(ah, ch[kf][nf], sa[nf], 0, 0, 0);
        sa[nf] = __builtin_amdgcn_mfma_f32_16x16x32_bf16(ah, cl[kf][nf], sa[nf], 0, 0, 0);
        sa[nf] = __builtin_amdgcn_mfma_f32_16x16x32_bf16(al, ch[kf][nf], sa[nf], 0, 0, 0);
      }
    }
    // exp (no max-shift needed: |S| <~ 50), row-sum partials, pack bf16
    unsigned pk[4][2];
    #pragma unroll
    for (int nf = 0; nf < 4; nf++){
      float e0 = __expf(sa[nf][0]);
      float e1 = __expf(sa[nf][1]);
      float e2 = __expf(sa[nf][2]);
      float e3 = __expf(sa[nf][3]);
      racc[nf] += (e0 + e1) + (e2 + e3);
      pk[nf][0] = (unsigned)f2bf(e0) | ((unsigned)f2bf(e1) << 16);
      pk[nf][1] = (unsigned)f2bf(e2) | ((unsigned)f2bf(e3) << 16);
    }
    __syncthreads();   // previous iteration's Pl/Xl reads complete
    #pragma unroll
    for (int nf = 0; nf < 4; nf++){
      unsigned* dst = (unsigned*)(&Pl[nf * 16 + lr][wv * 16 + 4 * g]);
      dst[0] = pk[nf][0];
      dst[1] = pk[nf][1];
    }
    #pragma unroll
    for (int u = 0; u < 8; u++)
      *(bf16x8*)(&Xl[sc + u * 32][smo]) = xst[u];
    __syncthreads();
    // PV: acc[n, c] += P[n, m-tile] * x_bot[m-tile, c]
    #pragma unroll
    for (int kf = 0; kf < 2; kf++){
      bf16x8 pa[4];
      #pragma unroll
      for (int nf = 0; nf < 4; nf++)
        pa[nf] = *(const bf16x8*)(&Pl[nf * 16 + lr][kf * 32 + 8 * g]);
      #pragma unroll
      for (int cf = 0; cf < 4; cf++){
        bf16x8 xb8 = *(const bf16x8*)(&Xl[wv * 64 + cf * 16 + lr][kf * 32 + 8 * g]);
        #pragma unroll
        for (int nf = 0; nf < 4; nf++)
          accO[nf][cf] = __builtin_amdgcn_mfma_f32_16x16x32_bf16(pa[nf], xb8, accO[nf][cf], 0, 0, 0);
      }
    }
  }
  // write unnormalized U (flat n*256+c == channels-first scrambled reshape)
  #pragma unroll
  for (int nf = 0; nf < 4; nf++)
    #pragma unroll
    for (int cf = 0; cf < 4; cf++)
      #pragma unroll
      for (int i = 0; i < 4; i++){
        int n = n0 + nf * 16 + 4 * g + i;
        int c = wv * 64 + cf * 16 + lr;
        U[((size_t)b << 20) + ((size_t)n << 8) + c] = accO[nf][cf][i];
      }
  // row sums -> rsum[b][n]
  #pragma unroll
  for (int nf = 0; nf < 4; nf++){
    float v = racc[nf];
    v += __shfl_xor(v, 16, 64);
    v += __shfl_xor(v, 32, 64);
    if (l < 16) rred[wv][nf][l] = v;
  }
  __syncthreads();
  if (t < 64){
    int nf = t >> 4, li = t & 15;
    float s = rred[0][nf][li] + rred[1][nf][li] + rred[2][nf][li] + rred[3][nf][li];
    rsum[((size_t)b << 12) + n0 + nf * 16 + li] = s;
  }
}

// ---------------------------------------------------------------------------
// k_rsum: Z[b] = sum_n rsum[b][n]
// ---------------------------------------------------------------------------
__global__ __launch_bounds__(256) void k_rsum(const float* __restrict__ r,
                                              float* __restrict__ Z){
  __shared__ float red[256];
  int b = blockIdx.x, t = threadIdx.x;
  float s = 0.f;
  for (int n = t; n < 4096; n += 256) s += r[((size_t)b << 12) + n];
  red[t] = s;
  __syncthreads();
  for (int o = 128; o > 0; o >>= 1){
    if (t < o) red[t] += red[t + o];
    __syncthreads();
  }
  if (t == 0) Z[b] = red[0];
}

// ---------------------------------------------------------------------------
extern "C" void kernel_launch(void* const* d_in, const int* in_sizes, int n_in,
                              void* d_out, int out_size, void* d_ws, size_t ws_size,
                              hipStream_t stream) {
  const float* x     = (const float*)d_in[0];
  const float* top_w = (const float*)d_in[1];
  const float* top_b = (const float*)d_in[2];
  const float* cen_w = (const float*)d_in[3];
  const float* cen_b = (const float*)d_in[4];
  const float* bot_w = (const float*)d_in[5];
  const float* bot_b = (const float*)d_in[6];
  const float* out_w = (const float*)d_in[7];
  const float* out_b = (const float*)d_in[8];
  float* out = (float*)d_out;

  constexpr size_t MB = 1ull << 20;
  char* ws = (char*)d_ws;
  float*          U    = (float*)(ws);                  // 32 MB
  unsigned short* tTh  = (unsigned short*)(ws + 32*MB); //  4 MB
  unsigned short* tTl  = (unsigned short*)(ws + 36*MB);
  unsigned short* cTh  = (unsigned short*)(ws + 40*MB);
  unsigned short* cTl  = (unsigned short*)(ws + 44*MB);
  unsigned short* xbot = (unsigned short*)(ws + 48*MB); // 16 MB
  unsigned short* xcl  = (unsigned short*)(ws + 64*MB); // 16 MB (reused as ycl)
  float*          wTt  = (float*)(ws + 80*MB);          // 64 KB
  float*          wTc  = (float*)(ws + 80*MB + 65536);
  unsigned short* apb  = (unsigned short*)(ws + 80*MB + 131072);   // 1.125 MB
  unsigned short* apo  = (unsigned short*)(ws + 80*MB + 131072 + 1179648);
  float*          r    = (float*)(ws + 80*MB + 131072 + 2*1179648); // 128 KB
  float*          Z    = (float*)(ws + 80*MB + 131072 + 2*1179648 + 65536);

  // 1. weight prep
  k_prep<<<2304, 256, 0, stream>>>(top_w, cen_w, bot_w, out_w, wTt, wTc, apb, apo);
  // 2. top/center 1x1 convs (fp32), stored transposed hi/lo bf16
  k_topcenter<<<dim3(16, 2, 8), 256, 0, stream>>>(x, wTt, wTc, top_b, cen_b,
                                                  tTh, tTl, cTh, cTl);
  // 3. x -> channels-last bf16
  k_trans<<<dim3(128, 8, 8), 256, 0, stream>>>(x, nullptr, nullptr, xcl);
  // 4. bottom 3x3 conv -> x_bottom bf16 [b][c][p]
  k_conv3<0><<<dim3(512), 256, 0, stream>>>(xcl, apb, bot_b, (void*)xbot);
  // 5. fused S/exp/PV -> U (unnormalized) + row sums
  k_pv<<<dim3(512), 256, 0, stream>>>(tTh, tTl, cTh, cTl, xbot, U, r);
  // 6. Z per batch
  k_rsum<<<8, 256, 0, stream>>>(r, Z);
  // 7. y = x + U/Z (scrambled reshape is identity on flat index) -> ycl bf16
  k_trans<<<dim3(128, 8, 8), 256, 0, stream>>>(x, U, Z, xcl);
  // 8. final 3x3 conv -> d_out fp32
  k_conv3<1><<<dim3(512), 256, 0, stream>>>(xcl, apo, out_b, (void*)out);
}